// Round 2
// baseline (209.302 us; speedup 1.0000x reference)
//
#include <hip/hip_runtime.h>
#include <hip/hip_bf16.h>

// ---------------------------------------------------------------------------
// WeightOnlyBlockwiseQuantizedLinear: out[m][n] = sum_s scaler[s][n] *
//   sum_{c<128} W[s][c][n] * x[m][s*128+c],  m = b*D+d (2048), n (4096)
//
// Strategy: dequantize W to bf16 (w*scaler, exact-int8 * fp32 -> bf16 rel err
// 2^-9), x fp32 -> bf16, then one m97-structure 128x128 MFMA GEMM.
// NOTE: integer inputs arrive as int32 (harness contract: "integer -> int*").
// ---------------------------------------------------------------------------

#define MDIM 2048
#define NDIM 4096
#define KDIM 4096
#define NBLK 32
#define BM 128
#define BN 128
#define BK 64

typedef __attribute__((ext_vector_type(8))) short bf16x8;
typedef __attribute__((ext_vector_type(4))) float f32x4;
typedef __attribute__((ext_vector_type(8))) unsigned short u16x8;

__device__ __forceinline__ unsigned short f2bf(float f) {
  unsigned u = __float_as_uint(f);
  u += 0x7fffu + ((u >> 16) & 1u);   // round-to-nearest-even
  return (unsigned short)(u >> 16);
}

__device__ __forceinline__ void gl_lds16(const void* g, void* l) {
  __builtin_amdgcn_global_load_lds(
      (const __attribute__((address_space(1))) unsigned int*)g,
      (__attribute__((address_space(3))) unsigned int*)l,
      16, 0, 0);
}

// ---- prep A: fp32 x -> bf16 ----------------------------------------------
__global__ void prep_a_kernel(const float* __restrict__ x,
                              unsigned short* __restrict__ ab) {
  int i = blockIdx.x * blockDim.x + threadIdx.x;  // group of 4 floats
  const float4 v = reinterpret_cast<const float4*>(x)[i];
  ushort4 hv;
  hv.x = f2bf(v.x); hv.y = f2bf(v.y); hv.z = f2bf(v.z); hv.w = f2bf(v.w);
  reinterpret_cast<ushort4*>(ab)[i] = hv;
}

// ---- prep B: W int32 [K][N] * scaler -> bf16 W^T [N][K] (LDS transpose) ---
__global__ void prep_b_kernel(const int* __restrict__ w,
                              const float* __restrict__ scaler,
                              unsigned short* __restrict__ bt) {
  __shared__ __align__(16) unsigned short tile[64][72];  // [n][k], +8 pad
  const int t = threadIdx.x;
  const int k0 = blockIdx.y * 64;
  const int n0 = blockIdx.x * 64;
  const int s = k0 >> 7;   // 64-tile never crosses a 128 block boundary
  {
    const int kl = t >> 2;   // 0..63
    const int nb = t & 3;    // group of 16 n
    const int nbase = n0 + nb * 16;
    const int4* src = reinterpret_cast<const int4*>(w + (size_t)(k0 + kl) * NDIM + nbase);
    const float4* scv = reinterpret_cast<const float4*>(scaler + (size_t)s * NDIM + nbase);
#pragma unroll
    for (int q = 0; q < 4; ++q) {
      const int4 v = src[q];
      const float4 sc = scv[q];
      tile[nb * 16 + q * 4 + 0][kl] = f2bf((float)v.x * sc.x);
      tile[nb * 16 + q * 4 + 1][kl] = f2bf((float)v.y * sc.y);
      tile[nb * 16 + q * 4 + 2][kl] = f2bf((float)v.z * sc.z);
      tile[nb * 16 + q * 4 + 3][kl] = f2bf((float)v.w * sc.w);
    }
  }
  __syncthreads();
  {
    const int nl = t >> 2;   // 0..63
#pragma unroll
    for (int q = 0; q < 2; ++q) {
      const int ch = (t & 3) * 2 + q;  // 0..7, 8 bf16 each
      u16x8 v = *reinterpret_cast<const u16x8*>(&tile[nl][ch * 8]);
      *reinterpret_cast<u16x8*>(bt + (size_t)(n0 + nl) * KDIM + k0 + ch * 8) = v;
    }
  }
}

// ---- main GEMM (m97 structure: 128x128 tile, BK=64, 4 waves 2x2) ----------
__global__ __launch_bounds__(256, 2)
void gemm_kernel(const unsigned short* __restrict__ ab,
                 const unsigned short* __restrict__ bt,
                 float* __restrict__ out) {
  __shared__ __align__(16) unsigned short lds_a[BM * BK];
  __shared__ __align__(16) unsigned short lds_b[BN * BK];

  const int t = threadIdx.x;
  const int lane = t & 63;
  const int wid = t >> 6;
  const int wm = wid >> 1;        // 0..1
  const int wn = wid & 1;         // 0..1
  const int lane15 = lane & 15;
  const int laneq = lane >> 4;    // 0..3
  const int swz = (lane & 7) << 4;  // == (row&7)<<4 for the rows this lane reads

  // XCD-aware block swizzle (512 % 8 == 0 -> bijective)
  const unsigned flat = blockIdx.x;
  const unsigned swzb = (flat & 7u) * 64u + (flat >> 3);
  const int ntile = swzb & 31;
  const int mtile = swzb >> 5;
  const int m0 = mtile * BM;
  const int n0 = ntile * BN;

  // staging: 256 thr x 16B = 32 rows x 128B per issue; pre-swizzled source
  const int srow = t >> 3;                    // 0..31
  const int sslot = (t & 7) ^ (srow & 7);     // inverse of read-side XOR
  const char* ga = (const char*)ab + ((size_t)(m0 + srow) * KDIM) * 2 + sslot * 16;
  const char* gb = (const char*)bt + ((size_t)(n0 + srow) * KDIM) * 2 + sslot * 16;
  const size_t rowstep = (size_t)32 * KDIM * 2;  // +32 rows per issue

  char* const la = (char*)lds_a;
  char* const lb = (char*)lds_b;
  const int ldst = wid * 8 * 128;             // wave-uniform LDS base part

  int offA[4], offB[4];
#pragma unroll
  for (int i = 0; i < 4; ++i) {
    offA[i] = (wm * 64 + i * 16 + lane15) * 128 + laneq * 16;
    offB[i] = (wn * 64 + i * 16 + lane15) * 128 + laneq * 16;
  }

  const f32x4 fzero = {0.f, 0.f, 0.f, 0.f};
  f32x4 acc[4][4];
#pragma unroll
  for (int m = 0; m < 4; ++m)
#pragma unroll
    for (int n = 0; n < 4; ++n) acc[m][n] = fzero;

  for (int kt = 0; kt < KDIM / BK; ++kt) {
    const size_t koff = (size_t)kt * (BK * 2);  // bytes along k
#pragma unroll
    for (int j = 0; j < 4; ++j) {
      gl_lds16(ga + koff + j * rowstep, la + ldst + j * 32 * 128);
      gl_lds16(gb + koff + j * rowstep, lb + ldst + j * 32 * 128);
    }
    __syncthreads();   // compiler drains vmcnt before barrier -> LDS ready
#pragma unroll
    for (int tt = 0; tt < 2; ++tt) {
      bf16x8 af[4], bf[4];
#pragma unroll
      for (int i = 0; i < 4; ++i) {
        af[i] = *(const bf16x8*)(la + ((offA[i] + tt * 64) ^ swz));
        bf[i] = *(const bf16x8*)(lb + ((offB[i] + tt * 64) ^ swz));
      }
#pragma unroll
      for (int m = 0; m < 4; ++m)
#pragma unroll
        for (int n = 0; n < 4; ++n)
          acc[m][n] = __builtin_amdgcn_mfma_f32_16x16x32_bf16(af[m], bf[n], acc[m][n], 0, 0, 0);
    }
    __syncthreads();   // all waves done reading LDS before restage
  }

  // epilogue: C/D layout col=lane&15, row=(lane>>4)*4+reg  [m89-verified]
#pragma unroll
  for (int m = 0; m < 4; ++m)
#pragma unroll
    for (int r = 0; r < 4; ++r) {
      const int row = m0 + wm * 64 + m * 16 + laneq * 4 + r;
      float* op = out + (size_t)row * NDIM + n0 + wn * 64 + lane15;
#pragma unroll
      for (int n = 0; n < 4; ++n) op[n * 16] = acc[m][n][r];
    }
}

// ---- correct-but-slow fallback if ws is too small -------------------------
__global__ void fallback_kernel(const float* __restrict__ x,
                                const int* __restrict__ w,
                                const float* __restrict__ scaler,
                                float* __restrict__ out) {
  const int n = blockIdx.x * 256 + threadIdx.x;
  const int m = blockIdx.y;
  float acc = 0.f;
  for (int s = 0; s < NBLK; ++s) {
    float p = 0.f;
    const float* xr = x + (size_t)m * KDIM + s * 128;
    const int* wr = w + (size_t)s * 128 * NDIM + n;
#pragma unroll 8
    for (int c = 0; c < 128; ++c) p += xr[c] * (float)wr[(size_t)c * NDIM];
    acc += p * scaler[s * NDIM + n];
  }
  out[(size_t)m * NDIM + n] = acc;
}

extern "C" void kernel_launch(void* const* d_in, const int* in_sizes, int n_in,
                              void* d_out, int out_size, void* d_ws, size_t ws_size,
                              hipStream_t stream) {
  (void)in_sizes; (void)n_in; (void)out_size;
  const float* x = (const float*)d_in[0];
  const int* w = (const int*)d_in[1];        // int8 values, int32 storage
  const float* sc = (const float*)d_in[2];
  float* out = (float*)d_out;

  const size_t need = (size_t)51 * 1024 * 1024;  // 16.8 MB A + 33.6 MB B^T
  if (ws_size >= need) {
    unsigned short* ab = (unsigned short*)d_ws;                    // [M][K] bf16
    unsigned short* bt = ab + (size_t)MDIM * KDIM;                 // [N][K] bf16
    prep_a_kernel<<<(MDIM * KDIM / 4) / 256, 256, 0, stream>>>(x, ab);
    prep_b_kernel<<<dim3(NDIM / 64, KDIM / 64), 256, 0, stream>>>(w, sc, bt);
    gemm_kernel<<<(MDIM / BM) * (NDIM / BN), 256, 0, stream>>>(ab, bt, out);
  } else {
    fallback_kernel<<<dim3(NDIM / 256, MDIM), 256, 0, stream>>>(x, w, sc, out);
  }
}

// Round 3
// 203.757 us; speedup vs baseline: 1.0272x; 1.0272x over previous
//
#include <hip/hip_runtime.h>
#include <hip/hip_bf16.h>

// ---------------------------------------------------------------------------
// WeightOnlyBlockwiseQuantizedLinear: out[m][n] = sum_s scaler[s][n] *
//   sum_{c<128} W[s][c][n] * x[m][s*128+c],  m = b*D+d (2048), n (4096)
//
// R3: dequant-to-bf16 prep (unchanged numerics, passed R2 with absmax 1.0 vs
// thr 3.56) + pipelined 4-phase/K-tile GEMM (T3+T4+T5): BM=128 BN=256 BK=64,
// 8 waves (2m x 4n, 64x64 each), 96 KB double-buffered LDS, counted vmcnt(6).
// ---------------------------------------------------------------------------

#define MDIM 2048
#define NDIM 4096
#define KDIM 4096
#define NBLK 32
#define BM 128
#define BN 256
#define BK 64
#define NT (KDIM / BK)   // 64 K-tiles

typedef __attribute__((ext_vector_type(8))) short bf16x8;
typedef __attribute__((ext_vector_type(4))) float f32x4;
typedef __attribute__((ext_vector_type(8))) unsigned short u16x8;

__device__ __forceinline__ unsigned short f2bf(float f) {
  unsigned u = __float_as_uint(f);
  u += 0x7fffu + ((u >> 16) & 1u);   // round-to-nearest-even
  return (unsigned short)(u >> 16);
}

__device__ __forceinline__ void gl_lds16(const void* g, void* l) {
  __builtin_amdgcn_global_load_lds(
      (const __attribute__((address_space(1))) unsigned int*)g,
      (__attribute__((address_space(3))) unsigned int*)l,
      16, 0, 0);
}

// ---- prep A: fp32 x -> bf16 ----------------------------------------------
__global__ void prep_a_kernel(const float* __restrict__ x,
                              unsigned short* __restrict__ ab) {
  int i = blockIdx.x * blockDim.x + threadIdx.x;  // group of 4 floats
  const float4 v = reinterpret_cast<const float4*>(x)[i];
  ushort4 hv;
  hv.x = f2bf(v.x); hv.y = f2bf(v.y); hv.z = f2bf(v.z); hv.w = f2bf(v.w);
  reinterpret_cast<ushort4*>(ab)[i] = hv;
}

// ---- prep B: W int32 [K][N] * scaler -> bf16 W^T [N][K] -------------------
// LDS transpose with k-position XOR swizzle: element (n,k) of the 64x64 tile
// stored at tile[n][k ^ (((n>>3)&7)<<3)] -> write banks spread 8->32 (was the
// R2 hotspot: (n*36)%32 is constant across the 4 n-groups of one write instr).
__global__ void prep_b_kernel(const int* __restrict__ w,
                              const float* __restrict__ scaler,
                              unsigned short* __restrict__ bt) {
  __shared__ __align__(16) unsigned short tile[64][72];
  const int t = threadIdx.x;
  const int k0 = blockIdx.y * 64;
  const int n0 = blockIdx.x * 64;
  const int s = k0 >> 7;   // 64-tile never crosses a 128 block boundary
  {
    const int kl = t >> 2;   // 0..63
    const int nb = t & 3;    // group of 16 n
    const int nbase = n0 + nb * 16;
    const int4* src = reinterpret_cast<const int4*>(w + (size_t)(k0 + kl) * NDIM + nbase);
    const float4* scv = reinterpret_cast<const float4*>(scaler + (size_t)s * NDIM + nbase);
#pragma unroll
    for (int q = 0; q < 4; ++q) {
      const int4 v = src[q];
      const float4 sc = scv[q];
      const int rbase = nb * 16 + q * 4;           // row (n within 64)
      const int swzr = ((rbase >> 3) & 7) << 3;    // same for rows rbase..rbase+3
      const int ckl = kl ^ swzr;
      tile[rbase + 0][ckl] = f2bf((float)v.x * sc.x);
      tile[rbase + 1][ckl] = f2bf((float)v.y * sc.y);
      tile[rbase + 2][ckl] = f2bf((float)v.z * sc.z);
      tile[rbase + 3][ckl] = f2bf((float)v.w * sc.w);
    }
  }
  __syncthreads();
  {
    const int nl = t >> 2;             // row 0..63
    const int swzn = (nl >> 3) & 7;
#pragma unroll
    for (int q = 0; q < 2; ++q) {
      const int ch = (t & 3) * 2 + q;  // chunk of 8 bf16 along k
      u16x8 v = *reinterpret_cast<const u16x8*>(&tile[nl][(ch ^ swzn) * 8]);
      *reinterpret_cast<u16x8*>(bt + (size_t)(n0 + nl) * KDIM + k0 + ch * 8) = v;
    }
  }
}

// ---- main GEMM: 4-phase pipelined, double-buffered, counted vmcnt ---------
#define MFMA_BF16 __builtin_amdgcn_mfma_f32_16x16x32_bf16

__global__ __launch_bounds__(512, 2)
void gemm_kernel(const unsigned short* __restrict__ ab,
                 const unsigned short* __restrict__ bt,
                 float* __restrict__ out) {
  // LDS layout: [A0 16K][A1 16K][B0 32K][B1 32K] = 96 KB
  __shared__ __align__(16) char lds[98304];

  const int t = threadIdx.x;
  const int lane = t & 63;
  const int wid = t >> 6;         // 0..7
  const int wm = wid >> 2;        // 0..1  (64-row band)
  const int wn = wid & 3;         // 0..3  (64-col band)
  const int lane15 = lane & 15;
  const int laneq = lane >> 4;    // 0..3
  const int swz = (lane & 7) << 4;

  // XCD-aware swizzle; 256 % 8 == 0 -> bijective
  const unsigned flat = blockIdx.x;
  const unsigned swzb = (flat & 7u) * 32u + (flat >> 3);
  const int ntile = swzb & 15;
  const int mtile = swzb >> 4;
  const int m0 = mtile * BM;
  const int n0 = ntile * BN;

  // staging: 512 thr x 16B = 8 KB = 64 rows x 128 B per issue
  const int srow = t >> 3;                    // 0..63
  const int sslot = (t & 7) ^ (srow & 7);     // inverse of read-side XOR
  const char* ga = (const char*)ab + ((size_t)(m0 + srow) * KDIM) * 2 + sslot * 16;
  const char* gb = (const char*)bt + ((size_t)(n0 + srow) * KDIM) * 2 + sslot * 16;
  const size_t rstep = (size_t)64 * KDIM * 2;  // +64 rows per issue

  char* const lA0 = lds + (size_t)wid * 1024;           // + c*16384
  char* const lB0 = lds + 32768 + (size_t)wid * 1024;   // + c*32768

#define STAGE(kt, c) do {                                   \
    const size_t ko_ = (size_t)(kt) * (BK * 2);             \
    char* a_ = lA0 + (c) * 16384;                           \
    char* b_ = lB0 + (c) * 32768;                           \
    gl_lds16(ga + ko_,             a_);                     \
    gl_lds16(ga + ko_ + rstep,     a_ + 8192);              \
    gl_lds16(gb + ko_,             b_);                     \
    gl_lds16(gb + ko_ + rstep,     b_ + 8192);              \
    gl_lds16(gb + ko_ + 2 * rstep, b_ + 16384);             \
    gl_lds16(gb + ko_ + 3 * rstep, b_ + 24576);             \
  } while (0)

  int offA[4], offB[4];
#pragma unroll
  for (int i = 0; i < 4; ++i) {
    offA[i] = (wm * 64 + i * 16 + lane15) * 128 + laneq * 16;
    offB[i] = (wn * 64 + i * 16 + lane15) * 128 + laneq * 16;
  }

  const f32x4 fzero = {0.f, 0.f, 0.f, 0.f};
  f32x4 acc[4][4];
#pragma unroll
  for (int m = 0; m < 4; ++m)
#pragma unroll
    for (int n = 0; n < 4; ++n) acc[m][n] = fzero;

  // prologue: tile 0 -> buf0, tile 1 -> buf1; wait tile 0 (6 newest stay out)
  STAGE(0, 0);
  STAGE(1, 1);
  asm volatile("s_waitcnt vmcnt(6)" ::: "memory");
  __builtin_amdgcn_s_barrier();

#define LDA(m, base) do {                                             \
    af[m][0] = *(const bf16x8*)((base) + ((offA[m]) ^ swz));          \
    af[m][1] = *(const bf16x8*)((base) + ((offA[m] + 64) ^ swz));     \
  } while (0)
#define LDB(n, base) do {                                             \
    bfr[n][0] = *(const bf16x8*)((base) + ((offB[n]) ^ swz));         \
    bfr[n][1] = *(const bf16x8*)((base) + ((offB[n] + 64) ^ swz));    \
  } while (0)
#define QUAD(mA, mB, nA, nB) do {                                     \
    __builtin_amdgcn_s_setprio(1);                                    \
    acc[mA][nA] = MFMA_BF16(af[mA][0], bfr[nA][0], acc[mA][nA], 0, 0, 0); \
    acc[mA][nB] = MFMA_BF16(af[mA][0], bfr[nB][0], acc[mA][nB], 0, 0, 0); \
    acc[mB][nA] = MFMA_BF16(af[mB][0], bfr[nA][0], acc[mB][nA], 0, 0, 0); \
    acc[mB][nB] = MFMA_BF16(af[mB][0], bfr[nB][0], acc[mB][nB], 0, 0, 0); \
    acc[mA][nA] = MFMA_BF16(af[mA][1], bfr[nA][1], acc[mA][nA], 0, 0, 0); \
    acc[mA][nB] = MFMA_BF16(af[mA][1], bfr[nB][1], acc[mA][nB], 0, 0, 0); \
    acc[mB][nA] = MFMA_BF16(af[mB][1], bfr[nA][1], acc[mB][nA], 0, 0, 0); \
    acc[mB][nB] = MFMA_BF16(af[mB][1], bfr[nB][1], acc[mB][nB], 0, 0, 0); \
    __builtin_amdgcn_s_setprio(0);                                    \
  } while (0)

#pragma unroll 2
  for (int t2 = 0; t2 < NT; ++t2) {
    const int c = t2 & 1;
    const char* lac = lds + c * 16384;
    const char* lbc = lds + 32768 + c * 32768;
    bf16x8 af[4][2], bfr[4][2];

    // P1: A01 + B01 -> quad (m01 x n01)
    LDA(0, lac); LDA(1, lac); LDB(0, lbc); LDB(1, lbc);
    __builtin_amdgcn_s_barrier();
    QUAD(0, 1, 0, 1);
    __builtin_amdgcn_s_barrier();

    // P2: B23 -> quad (m01 x n23)
    LDB(2, lbc); LDB(3, lbc);
    __builtin_amdgcn_s_barrier();
    QUAD(0, 1, 2, 3);
    __builtin_amdgcn_s_barrier();

    // P3: A23 -> quad (m23 x n23)
    LDA(2, lac); LDA(3, lac);
    __builtin_amdgcn_s_barrier();
    QUAD(2, 3, 2, 3);
    __builtin_amdgcn_s_barrier();
    __builtin_amdgcn_sched_barrier(0);  // pin stage below this barrier

    // P4: stage t2+2 into buf c (its readers all finished at P3's barrier),
    // compute last quad from registers, then counted vmcnt: the 6 newest
    // loads (tile t2+2) stay in flight; tile t2+1 is forced to land.
    if (t2 + 2 < NT) STAGE(t2 + 2, c);
    QUAD(2, 3, 0, 1);
    if (t2 + 2 < NT) {
      asm volatile("s_waitcnt vmcnt(6)" ::: "memory");
    } else {
      asm volatile("s_waitcnt vmcnt(0)" ::: "memory");
    }
    __builtin_amdgcn_s_barrier();
  }

  // epilogue: C/D layout col=lane&15, row=(lane>>4)*4+reg  [m89-verified]
#pragma unroll
  for (int m = 0; m < 4; ++m)
#pragma unroll
    for (int r = 0; r < 4; ++r) {
      const int row = m0 + wm * 64 + m * 16 + laneq * 4 + r;
      float* op = out + (size_t)row * NDIM + n0 + wn * 64 + lane15;
#pragma unroll
      for (int n = 0; n < 4; ++n) op[n * 16] = acc[m][n][r];
    }
#undef STAGE
#undef LDA
#undef LDB
#undef QUAD
}

// ---- correct-but-slow fallback if ws is too small -------------------------
__global__ void fallback_kernel(const float* __restrict__ x,
                                const int* __restrict__ w,
                                const float* __restrict__ scaler,
                                float* __restrict__ out) {
  const int n = blockIdx.x * 256 + threadIdx.x;
  const int m = blockIdx.y;
  float acc = 0.f;
  for (int s = 0; s < NBLK; ++s) {
    float p = 0.f;
    const float* xr = x + (size_t)m * KDIM + s * 128;
    const int* wr = w + (size_t)s * 128 * NDIM + n;
#pragma unroll 8
    for (int c = 0; c < 128; ++c) p += xr[c] * (float)wr[(size_t)c * NDIM];
    acc += p * scaler[s * NDIM + n];
  }
  out[(size_t)m * NDIM + n] = acc;
}

extern "C" void kernel_launch(void* const* d_in, const int* in_sizes, int n_in,
                              void* d_out, int out_size, void* d_ws, size_t ws_size,
                              hipStream_t stream) {
  (void)in_sizes; (void)n_in; (void)out_size;
  const float* x = (const float*)d_in[0];
  const int* w = (const int*)d_in[1];        // int8 values, int32 storage
  const float* sc = (const float*)d_in[2];
  float* out = (float*)d_out;

  const size_t need = (size_t)51 * 1024 * 1024;  // 16.8 MB A + 33.6 MB B^T
  if (ws_size >= need) {
    unsigned short* ab = (unsigned short*)d_ws;            // [M][K] bf16
    unsigned short* bt = ab + (size_t)MDIM * KDIM;         // [N][K] bf16
    prep_a_kernel<<<(MDIM * KDIM / 4) / 256, 256, 0, stream>>>(x, ab);
    prep_b_kernel<<<dim3(NDIM / 64, KDIM / 64), 256, 0, stream>>>(w, sc, bt);
    gemm_kernel<<<(MDIM / BM) * (NDIM / BN), 512, 0, stream>>>(ab, bt, out);
  } else {
    fallback_kernel<<<dim3(NDIM / 256, MDIM), 256, 0, stream>>>(x, w, sc, out);
  }
}